// Round 19
// baseline (69.658 us; speedup 1.0000x reference)
//
#include <hip/hip_runtime.h>
#include <hip/hip_fp16.h>
#include <math.h>

#define L_SEQ 4096
#define BSZ   4
#define DIM   1024
#define NDIM  16
#define BD    (BSZ*DIM)
#define CHUNK 40      // outputs per wave; LDS = CHUNK*512B = 20KB -> 8 blocks/CU
#define HALO  48      // q^48 truncation ~3.3x the (invisible) H=64 level; safe margin
#define NCHUNK 103    // ceil(4096/40); last chunk = 16 rows
#define NLGRP  52     // ceil(103/2); last lgrp has a phantom chunk

// Round 19: R16's balanced direction-split (best: 58.2us) retuned to
// (CHUNK=40, HALO=48). Work/output 96->102 (+6%) but LDS 32KB->20KB gives
// 8 blocks/CU = 32 waves/CU (+60% vs R16's LDS-capped 20). Cross-round
// busyfrac evidence (R16 58% @20w, R17 68% @32w) predicts net ~15% win.
// Waves 0,1 = FWD chunks A,B; waves 2,3 = BWD chunks A,B, all 128-ish steps
// concurrently; partials meet in f16 LDS; one barrier; combine+store.
__global__ __launch_bounds__(256) void k_ema_split(
    const float* __restrict__ x,
    const float* __restrict__ delta,
    const float* __restrict__ alpha,
    const float* __restrict__ beta,
    const float* __restrict__ gamma,
    const float* __restrict__ omega,
    float* __restrict__ out)
{
    __shared__ __half accF[2][CHUNK][64];   // 10 KB: fwd partial (+residual)
    __shared__ __half accB[2][CHUNK][64];   // 10 KB: bwd partial

    const int lane  = threadIdx.x & 63;
    const int wv    = threadIdx.x >> 6;     // 0..3
    const int pair  = wv & 1;               // chunk A/B within the block
    const int dir   = wv >> 1;              // 0 = fwd, 1 = bwd
    const int dtile = blockIdx.x & 15;      // 16 tiles of 64 d's
    const int b     = (blockIdx.x >> 4) & 3;
    const int lgrp  = blockIdx.x >> 6;      // 0..51
    const int chunk = lgrp * 2 + pair;      // 0..103 (103 = phantom)
    const int i0    = chunk * CHUNK;
    const int lm    = (i0 < L_SEQ) ? ((L_SEQ - i0 < CHUNK) ? (L_SEQ - i0) : CHUNK) : 0;
    const int dg    = dtile * 64 + lane;    // 0..1023
    const int col   = b * DIM + dg;         // column in (L, B*D)

    // per-direction params
    const int d2 = (dir == 0) ? dg : (DIM + dg);
    float h[NDIM], q[NDIM], wt[NDIM];
    #pragma unroll
    for (int n = 0; n < NDIM; ++n) {
        const int idx = d2 * NDIM + n;
        const float p  = 1.0f / (1.0f + __expf(-delta[idx]));
        const float sa = 1.0f / (1.0f + __expf(-alpha[idx]));
        q[n]  = 1.0f - p * sa;                       // decay in (0,1)
        wt[n] = p * beta[idx] * gamma[idx] * 0.25f;  // scale = 1/sqrt(16)
        h[n]  = 0.0f;
    }

    if (dir == 0 && lm > 0) {
        const float omega_d = omega[dg];
        // fwd halo: [max(i0-H,0), i0)  (len 0, 40, or 48 - all mult. of 8)
        {
            int start = i0 - HALO; if (start < 0) start = 0;
            #pragma unroll 8
            for (int i = start; i < i0; ++i) {
                const float xv = x[(size_t)i * BD + col];
                #pragma unroll
                for (int n = 0; n < NDIM; ++n) h[n] = fmaf(q[n], h[n], xv);
            }
        }
        // fwd main: emit fwd contribution + residual into accF (f16)
        #pragma unroll 8
        for (int j = 0; j < lm; ++j) {
            const float xv = x[(size_t)(i0 + j) * BD + col];
            float a0 = xv * omega_d, a1 = 0.0f;
            #pragma unroll
            for (int n = 0; n < NDIM; n += 2) {
                h[n]   = fmaf(q[n],   h[n],   xv);
                h[n+1] = fmaf(q[n+1], h[n+1], xv);
                a0 = fmaf(wt[n],   h[n],   a0);
                a1 = fmaf(wt[n+1], h[n+1], a1);
            }
            accF[pair][j][lane] = __float2half_rn(a0 + a1);
        }
    } else if (dir == 1 && lm > 0) {
        // bwd halo: [i0+lm, min(i0+lm+H, L)) descending (len mult. of 8)
        {
            int end = i0 + lm + HALO; if (end > L_SEQ) end = L_SEQ;
            #pragma unroll 8
            for (int i = end - 1; i >= i0 + lm; --i) {
                const float xv = x[(size_t)i * BD + col];
                #pragma unroll
                for (int n = 0; n < NDIM; ++n) h[n] = fmaf(q[n], h[n], xv);
            }
        }
        // bwd main: descending, emit bwd contribution into accB (f16)
        #pragma unroll 8
        for (int j = lm - 1; j >= 0; --j) {
            const float xv = x[(size_t)(i0 + j) * BD + col];
            float a0 = 0.0f, a1 = 0.0f;
            #pragma unroll
            for (int n = 0; n < NDIM; n += 2) {
                h[n]   = fmaf(q[n],   h[n],   xv);
                h[n+1] = fmaf(q[n+1], h[n+1], xv);
                a0 = fmaf(wt[n],   h[n],   a0);
                a1 = fmaf(wt[n+1], h[n+1], a1);
            }
            accB[pair][j][lane] = __float2half_rn(a0 + a1);
        }
    }
    __syncthreads();   // single block-wide barrier, reached by all waves

    // combine + coalesced store: rows [base, base+span), wave-strided
    const int base = lgrp * 2 * CHUNK;
    int span = L_SEQ - base; if (span > 2 * CHUNK) span = 2 * CHUNK;
    #pragma unroll 4
    for (int r = wv; r < span; r += 4) {
        const int pc = (r >= CHUNK) ? 1 : 0;
        const int j  = r - pc * CHUNK;
        const float v = __half2float(accF[pc][j][lane])
                      + __half2float(accB[pc][j][lane]);
        out[(size_t)(base + r) * BD + col] = v;
    }
}

extern "C" void kernel_launch(void* const* d_in, const int* in_sizes, int n_in,
                              void* d_out, int out_size, void* d_ws, size_t ws_size,
                              hipStream_t stream) {
    const float* x     = (const float*)d_in[0];
    const float* delta = (const float*)d_in[1];
    const float* alpha = (const float*)d_in[2];
    const float* beta  = (const float*)d_in[3];
    const float* gamma = (const float*)d_in[4];
    const float* omega = (const float*)d_in[5];
    float* out = (float*)d_out;

    // 52 chunk-pairs x 4 batches x 16 d-tiles = 3328 blocks of 256 threads;
    // 20KB LDS -> 8 blocks/CU (32 waves/CU).
    k_ema_split<<<NLGRP * 64, 256, 0, stream>>>(x, delta, alpha, beta, gamma, omega, out);
}

// Round 21
// 61.376 us; speedup vs baseline: 1.1349x; 1.1349x over previous
//
#include <hip/hip_runtime.h>
#include <hip/hip_fp16.h>
#include <math.h>

#define L_SEQ 4096
#define BSZ   4
#define DIM   1024
#define NDIM  16
#define BD    (BSZ*DIM)
#define CHUNK 64      // outputs per wave (halo = 33% of FMA work)
#define HALO  64      // q^64 <= 0.008 worst-case -> err ~0.03 << 0.357

typedef float f32x2 __attribute__((ext_vector_type(2)));

// pk-FMA helpers: d = a*b + c over a float2 pair, one VOP3P instruction.
__device__ __forceinline__ void pk_fma(f32x2& acc_or_h, const f32x2 a, const f32x2 c) {
    // acc_or_h = a * acc_or_h + c   (h-update form: h = q*h + x)
    asm("v_pk_fma_f32 %0, %1, %0, %2" : "+v"(acc_or_h) : "v"(a), "v"(c));
}
__device__ __forceinline__ void pk_acc(f32x2& acc, const f32x2 w, const f32x2 h) {
    // acc = w * h + acc
    asm("v_pk_fma_f32 %0, %1, %2, %0" : "+v"(acc) : "v"(w), "v"(h));
}

// Round 20/21: R16's exact structure (best: 58.2us; issue-bound, busy-time
// ~40us) with the inner math in packed FP32. v_pk_fma_f32 (VOP3P) does 2
// FMA/instr - the 16 EMA states live in 8 float2 pairs, so each time-step is
// 8 pk h-updates + 8 pk acc-updates instead of 32 scalar FMAs. Targets the
// instruction-issue floor directly; structure, LDS, grid identical to R16.
__global__ __launch_bounds__(256) void k_ema_split(
    const float* __restrict__ x,
    const float* __restrict__ delta,
    const float* __restrict__ alpha,
    const float* __restrict__ beta,
    const float* __restrict__ gamma,
    const float* __restrict__ omega,
    float* __restrict__ out)
{
    __shared__ __half accF[2][CHUNK][64];   // 16 KB: fwd partial (+residual)
    __shared__ __half accB[2][CHUNK][64];   // 16 KB: bwd partial

    const int lane  = threadIdx.x & 63;
    const int wv    = threadIdx.x >> 6;     // 0..3
    const int pair  = wv & 1;               // chunk A/B within the block
    const int dir   = wv >> 1;              // 0 = fwd, 1 = bwd
    const int dtile = blockIdx.x & 15;      // 16 tiles of 64 d's
    const int b     = (blockIdx.x >> 4) & 3;
    const int lgrp  = blockIdx.x >> 6;      // 0..31 (pairs of 64-chunks)
    const int chunk = lgrp * 2 + pair;      // 0..63
    const int i0    = chunk * CHUNK;
    const int dg    = dtile * 64 + lane;    // 0..1023
    const int col   = b * DIM + dg;         // column in (L, B*D)

    // per-direction params, packed: state pair k = (2k, 2k+1)
    const int d2 = (dir == 0) ? dg : (DIM + dg);
    f32x2 h2[8], q2[8], w2[8];
    #pragma unroll
    for (int k = 0; k < 8; ++k) {
        const int ia = d2 * NDIM + 2 * k;
        const float da = delta[ia],     db = delta[ia + 1];
        const float aa = alpha[ia],     ab = alpha[ia + 1];
        const float ba = beta[ia],      bb = beta[ia + 1];
        const float ga = gamma[ia],     gb = gamma[ia + 1];
        const float pa = 1.0f / (1.0f + __expf(-da));
        const float pb = 1.0f / (1.0f + __expf(-db));
        const float sa = 1.0f / (1.0f + __expf(-aa));
        const float sb = 1.0f / (1.0f + __expf(-ab));
        q2[k] = (f32x2){1.0f - pa * sa, 1.0f - pb * sb};
        w2[k] = (f32x2){pa * ba * ga * 0.25f, pb * bb * gb * 0.25f};
        h2[k] = (f32x2){0.0f, 0.0f};
    }

    if (dir == 0) {
        const float omega_d = omega[dg];
        // fwd halo: [i0-64, i0) ascending (empty for chunk 0 - exact zero init)
        if (i0 > 0) {
            const int hb = i0 - HALO;
            #pragma unroll 8
            for (int r = 0; r < HALO; ++r) {
                const float xv = x[(size_t)(hb + r) * BD + col];
                const f32x2 x2 = (f32x2){xv, xv};
                #pragma unroll
                for (int k = 0; k < 8; ++k) pk_fma(h2[k], q2[k], x2);
            }
        }
        // fwd main: emit fwd contribution + residual into accF (f16)
        #pragma unroll 8
        for (int j = 0; j < CHUNK; ++j) {
            const float xv = x[(size_t)(i0 + j) * BD + col];
            const f32x2 x2 = (f32x2){xv, xv};
            f32x2 aA = (f32x2){xv * omega_d, 0.0f};
            f32x2 aB = (f32x2){0.0f, 0.0f};
            #pragma unroll
            for (int k = 0; k < 8; ++k) pk_fma(h2[k], q2[k], x2);
            #pragma unroll
            for (int k = 0; k < 8; k += 2) {
                pk_acc(aA, w2[k],     h2[k]);
                pk_acc(aB, w2[k + 1], h2[k + 1]);
            }
            const f32x2 s = aA + aB;
            accF[pair][j][lane] = __float2half_rn(s.x + s.y);
        }
    } else {
        // bwd halo: [i0+C, i0+C+64) descending (empty for last chunk - exact)
        if (i0 + CHUNK < L_SEQ) {
            const int tb = i0 + CHUNK + HALO - 1;
            #pragma unroll 8
            for (int r = 0; r < HALO; ++r) {
                const float xv = x[(size_t)(tb - r) * BD + col];
                const f32x2 x2 = (f32x2){xv, xv};
                #pragma unroll
                for (int k = 0; k < 8; ++k) pk_fma(h2[k], q2[k], x2);
            }
        }
        // bwd main: descending, emit bwd contribution into accB (f16)
        #pragma unroll 8
        for (int j = CHUNK - 1; j >= 0; --j) {
            const float xv = x[(size_t)(i0 + j) * BD + col];
            const f32x2 x2 = (f32x2){xv, xv};
            f32x2 aA = (f32x2){0.0f, 0.0f};
            f32x2 aB = (f32x2){0.0f, 0.0f};
            #pragma unroll
            for (int k = 0; k < 8; ++k) pk_fma(h2[k], q2[k], x2);
            #pragma unroll
            for (int k = 0; k < 8; k += 2) {
                pk_acc(aA, w2[k],     h2[k]);
                pk_acc(aB, w2[k + 1], h2[k + 1]);
            }
            const f32x2 s = aA + aB;
            accB[pair][j][lane] = __float2half_rn(s.x + s.y);
        }
    }
    __syncthreads();

    // combine + coalesced store: 128 rows across 4 waves (32 each)
    const int base = lgrp * 2 * CHUNK;      // first row of chunk A
    #pragma unroll 8
    for (int k = 0; k < 32; ++k) {
        const int row = wv * 32 + k;        // 0..127
        const int pc  = row >> 6;           // which chunk
        const int j   = row & 63;
        const float v = __half2float(accF[pc][j][lane])
                      + __half2float(accB[pc][j][lane]);
        out[(size_t)(base + row) * BD + col] = v;
    }
}

extern "C" void kernel_launch(void* const* d_in, const int* in_sizes, int n_in,
                              void* d_out, int out_size, void* d_ws, size_t ws_size,
                              hipStream_t stream) {
    const float* x     = (const float*)d_in[0];
    const float* delta = (const float*)d_in[1];
    const float* alpha = (const float*)d_in[2];
    const float* beta  = (const float*)d_in[3];
    const float* gamma = (const float*)d_in[4];
    const float* omega = (const float*)d_in[5];
    float* out = (float*)d_out;

    // 32 chunk-pairs x 4 batches x 16 d-tiles = 2048 blocks of 256 threads
    // (32KB LDS -> 5 blocks/CU, R16's best-measured resident shape).
    k_ema_split<<<2048, 256, 0, stream>>>(x, delta, alpha, beta, gamma, omega, out);
}

// Round 22
// 54.009 us; speedup vs baseline: 1.2897x; 1.1364x over previous
//
#include <hip/hip_runtime.h>
#include <hip/hip_fp16.h>
#include <math.h>

#define L_SEQ 4096
#define BSZ   4
#define DIM   1024
#define NDIM  16
#define BD    (BSZ*DIM)
#define CHUNK 64      // outputs per wave
#define HALO  48      // q^48 <= ~0.03 worst-case; truncation err <= ~0.1 << 0.357

// Round 22: R16's exact structure (best measured: 58.2us) with HALO 64->48.
// Work/output 96->88 FMA (-8%); trip counts stay fixed (48 = 6x8), chunk
// geometry unchanged (C=64 divides L). R21 taught: v_pk_fma_f32 is
// issue-neutral on CDNA4 (157.3TF spec = scalar FMA rate) - scalar FMA is
// optimal codegen. Waves 0,1 = FWD chunks A,B; waves 2,3 = BWD chunks A,B
// concurrently; partials meet in f16 LDS; one barrier; combine+store.
__global__ __launch_bounds__(256) void k_ema_split(
    const float* __restrict__ x,
    const float* __restrict__ delta,
    const float* __restrict__ alpha,
    const float* __restrict__ beta,
    const float* __restrict__ gamma,
    const float* __restrict__ omega,
    float* __restrict__ out)
{
    __shared__ __half accF[2][CHUNK][64];   // 16 KB: fwd partial (+residual)
    __shared__ __half accB[2][CHUNK][64];   // 16 KB: bwd partial

    const int lane  = threadIdx.x & 63;
    const int wv    = threadIdx.x >> 6;     // 0..3
    const int pair  = wv & 1;               // chunk A/B within the block
    const int dir   = wv >> 1;              // 0 = fwd, 1 = bwd
    const int dtile = blockIdx.x & 15;      // 16 tiles of 64 d's
    const int b     = (blockIdx.x >> 4) & 3;
    const int lgrp  = blockIdx.x >> 6;      // 0..31 (pairs of 64-chunks)
    const int chunk = lgrp * 2 + pair;      // 0..63
    const int i0    = chunk * CHUNK;
    const int dg    = dtile * 64 + lane;    // 0..1023
    const int col   = b * DIM + dg;         // column in (L, B*D)

    // per-direction params
    const int d2 = (dir == 0) ? dg : (DIM + dg);
    float h[NDIM], q[NDIM], wt[NDIM];
    #pragma unroll
    for (int n = 0; n < NDIM; ++n) {
        const int idx = d2 * NDIM + n;
        const float p  = 1.0f / (1.0f + __expf(-delta[idx]));
        const float sa = 1.0f / (1.0f + __expf(-alpha[idx]));
        q[n]  = 1.0f - p * sa;                       // decay in (0,1)
        wt[n] = p * beta[idx] * gamma[idx] * 0.25f;  // scale = 1/sqrt(16)
        h[n]  = 0.0f;
    }

    if (dir == 0) {
        const float omega_d = omega[dg];
        // fwd halo: [i0-48, i0) ascending (empty for chunk 0 - exact zero init)
        if (i0 > 0) {
            const int hb = i0 - HALO;
            #pragma unroll 8
            for (int r = 0; r < HALO; ++r) {
                const float xv = x[(size_t)(hb + r) * BD + col];
                #pragma unroll
                for (int n = 0; n < NDIM; ++n) h[n] = fmaf(q[n], h[n], xv);
            }
        }
        // fwd main: emit fwd contribution + residual into accF (f16)
        #pragma unroll 8
        for (int j = 0; j < CHUNK; ++j) {
            const float xv = x[(size_t)(i0 + j) * BD + col];
            float a0 = xv * omega_d, a1 = 0.0f;
            #pragma unroll
            for (int n = 0; n < NDIM; n += 2) {
                h[n]   = fmaf(q[n],   h[n],   xv);
                h[n+1] = fmaf(q[n+1], h[n+1], xv);
                a0 = fmaf(wt[n],   h[n],   a0);
                a1 = fmaf(wt[n+1], h[n+1], a1);
            }
            accF[pair][j][lane] = __float2half_rn(a0 + a1);
        }
    } else {
        // bwd halo: [i0+C, i0+C+48) descending (empty for last chunk - exact)
        if (i0 + CHUNK < L_SEQ) {
            const int tb = i0 + CHUNK + HALO - 1;
            #pragma unroll 8
            for (int r = 0; r < HALO; ++r) {
                const float xv = x[(size_t)(tb - r) * BD + col];
                #pragma unroll
                for (int n = 0; n < NDIM; ++n) h[n] = fmaf(q[n], h[n], xv);
            }
        }
        // bwd main: descending, emit bwd contribution into accB (f16)
        #pragma unroll 8
        for (int j = CHUNK - 1; j >= 0; --j) {
            const float xv = x[(size_t)(i0 + j) * BD + col];
            float a0 = 0.0f, a1 = 0.0f;
            #pragma unroll
            for (int n = 0; n < NDIM; n += 2) {
                h[n]   = fmaf(q[n],   h[n],   xv);
                h[n+1] = fmaf(q[n+1], h[n+1], xv);
                a0 = fmaf(wt[n],   h[n],   a0);
                a1 = fmaf(wt[n+1], h[n+1], a1);
            }
            accB[pair][j][lane] = __float2half_rn(a0 + a1);
        }
    }
    __syncthreads();

    // combine + coalesced store: 128 rows across 4 waves (32 each)
    const int base = lgrp * 2 * CHUNK;      // first row of chunk A
    #pragma unroll 8
    for (int k = 0; k < 32; ++k) {
        const int row = wv * 32 + k;        // 0..127
        const int pc  = row >> 6;           // which chunk
        const int j   = row & 63;
        const float v = __half2float(accF[pc][j][lane])
                      + __half2float(accB[pc][j][lane]);
        out[(size_t)(base + row) * BD + col] = v;
    }
}

extern "C" void kernel_launch(void* const* d_in, const int* in_sizes, int n_in,
                              void* d_out, int out_size, void* d_ws, size_t ws_size,
                              hipStream_t stream) {
    const float* x     = (const float*)d_in[0];
    const float* delta = (const float*)d_in[1];
    const float* alpha = (const float*)d_in[2];
    const float* beta  = (const float*)d_in[3];
    const float* gamma = (const float*)d_in[4];
    const float* omega = (const float*)d_in[5];
    float* out = (float*)d_out;

    // 32 chunk-pairs x 4 batches x 16 d-tiles = 2048 blocks of 256 threads
    // (32KB LDS -> 5 blocks/CU, R16's best-measured resident shape).
    k_ema_split<<<2048, 256, 0, stream>>>(x, delta, alpha, beta, gamma, omega, out);
}